// Round 14
// baseline (137.240 us; speedup 1.0000x reference)
//
#include <hip/hip_runtime.h>
#include <hip/hip_bf16.h>
#include <stdint.h>

typedef int v4i __attribute__((ext_vector_type(4)));

#define GPTR(p) ((const __attribute__((address_space(1))) void*)(p))
#define LPTR(p) ((__attribute__((address_space(3))) void*)(p))

__device__ __forceinline__ float wave_max(float m) {
#pragma unroll
  for (int off = 32; off > 0; off >>= 1)
    m = fmaxf(m, __shfl_xor(m, off, 64));
  return m;
}

// tanh-form GELU via sigmoid. |g - gelu_erf| <= ~3e-4. Validated r7.
__device__ __forceinline__ float gelu_tanh(float x) {
  const float x2 = x * x;
  const float u = x * fmaf(0.044715f, x2, 1.0f);
  const float e = exp2f(-2.3022082f * u);
  return x * __builtin_amdgcn_rcpf(1.0f + e);
}

// fused absmax of {x*smul, w1, w2} -> scal[0..2], one atomic per block
__global__ void absmax3_kernel(const float* __restrict__ x, int nx4,
                               const float* __restrict__ smul,
                               const float* __restrict__ w1, int nw14,
                               const float* __restrict__ w2, int nw24,
                               unsigned* __restrict__ scal) {
  __shared__ float red[4];
  const int bid = blockIdx.x;
  const float4* s4;
  int n4, b0, nb;
  float s = 1.0f;
  unsigned* dst;
  if (bid < 512)      { s4 = (const float4*)x;  n4 = nx4;  s = smul[0]; dst = scal;     b0 = bid;       nb = 512; }
  else if (bid < 640) { s4 = (const float4*)w1; n4 = nw14;              dst = scal + 1; b0 = bid - 512; nb = 128; }
  else                { s4 = (const float4*)w2; n4 = nw24;              dst = scal + 2; b0 = bid - 640; nb = 128; }
  float m = 0.0f;
  const int stride = nb * blockDim.x;
  for (int i = b0 * blockDim.x + threadIdx.x; i < n4; i += stride) {
    float4 v = s4[i];
    m = fmaxf(m, fabsf(v.x * s));
    m = fmaxf(m, fabsf(v.y * s));
    m = fmaxf(m, fabsf(v.z * s));
    m = fmaxf(m, fabsf(v.w * s));
  }
  m = wave_max(m);
  if ((threadIdx.x & 63) == 0) red[threadIdx.x >> 6] = m;
  __syncthreads();
  if (threadIdx.x == 0)
    atomicMax(dst, __float_as_uint(fmaxf(fmaxf(red[0], red[1]), fmaxf(red[2], red[3]))));
}

// fused quantize of {x*smul, w1, w2} -> qx, qw1, qw2
__global__ void quantize3_kernel(const float* __restrict__ x, int nx4,
                                 const float* __restrict__ smul,
                                 const float* __restrict__ w1, int nw14,
                                 const float* __restrict__ w2, int nw24,
                                 const unsigned* __restrict__ scal,
                                 int8_t* __restrict__ qx,
                                 int8_t* __restrict__ qw1,
                                 int8_t* __restrict__ qw2) {
  const int bid = blockIdx.x;
  const float4* s4;
  char4* d4;
  int n4, b0, nb;
  float s = 1.0f, mx;
  if (bid < 2048)      { s4 = (const float4*)x;  d4 = (char4*)qx;  n4 = nx4;  s = smul[0]; mx = __uint_as_float(scal[0]); b0 = bid;        nb = 2048; }
  else if (bid < 2176) { s4 = (const float4*)w1; d4 = (char4*)qw1; n4 = nw14;              mx = __uint_as_float(scal[1]); b0 = bid - 2048; nb = 128; }
  else                 { s4 = (const float4*)w2; d4 = (char4*)qw2; n4 = nw24;              mx = __uint_as_float(scal[2]); b0 = bid - 2176; nb = 128; }
  const float scale = mx / 127.0f;  // exact IEEE divide, matches reference
  const int stride = nb * blockDim.x;
  for (int i = b0 * blockDim.x + threadIdx.x; i < n4; i += stride) {
    float4 v = s4[i];
    char4 qq;
    qq.x = (signed char)(int)rintf(fminf(fmaxf((v.x * s) / scale, -128.0f), 127.0f));
    qq.y = (signed char)(int)rintf(fminf(fmaxf((v.y * s) / scale, -128.0f), 127.0f));
    qq.z = (signed char)(int)rintf(fminf(fmaxf((v.z * s) / scale, -128.0f), 127.0f));
    qq.w = (signed char)(int)rintf(fminf(fmaxf((v.w * s) / scale, -128.0f), 127.0f));
    d4[i] = qq;
  }
}

// reduce partial raw-f maxima -> s_h numerator = max|gelu| (r5-verified math)
__global__ void reduce_scale_kernel(const float* __restrict__ partial, int n,
                                    unsigned* __restrict__ scal) {
  __shared__ float red[4];
  float m = -3.4e38f;
  for (int i = threadIdx.x; i < n; i += blockDim.x) m = fmaxf(m, partial[i]);
  m = wave_max(m);
  if ((threadIdx.x & 63) == 0) red[threadIdx.x >> 6] = m;
  __syncthreads();
  if (threadIdx.x == 0) {
    m = fmaxf(fmaxf(red[0], red[1]), fmaxf(red[2], red[3]));
    const float sx = __uint_as_float(scal[0]) / 127.0f;
    const float sw = __uint_as_float(scal[1]) / 127.0f;
    const float max_f = m * (sw * sx);
    scal[3] = __float_as_uint(fmaxf(gelu_tanh(max_f), 0.1699702f));
  }
}

// ---------------------------------------------------------------------------
// fc1: C = qx[M,384] @ qw1[1536,384]^T. FULL-K single-stage: all 6 BK=64
// chunks of the 64-row A strip (24 KB) and 128-row B panel (48 KB) staged
// up-front (18 global_load_lds per thread), ONE vmcnt(0) + ONE barrier,
// then 6 K-steps of pure ds_read+MFMA with no barriers/waits. This removes
// the per-K-step HBM round trip that r3-r13 all paid (the ~3800 cyc/kt).
// 256 threads = 4 waves (2M x 2N), wave tile 32x64, 8 MFMA/kt.
// C frag layout (verified r1-r3): n = wc*64 + fc*16 + (lane&15),
//                                 m = wr*32 + fr*16 + (lane>>4)*4 + reg.
// EPI 0: per-block max of raw int-max(acc)+bias -> partial
// EPI 1: qh = rint(clip(gelu(f*s1)/s_h)) int8 via swizzled LDS repack
// ---------------------------------------------------------------------------
template <int EPI>
__global__ __launch_bounds__(256, 2)
void fc1_kernel(const int8_t* __restrict__ A, const int8_t* __restrict__ B,
                const float* __restrict__ bias, const unsigned* __restrict__ scal,
                float* __restrict__ partial, int8_t* __restrict__ qh,
                int N, int K, int GN) {
  __shared__ __align__(16) int8_t lA[6][64 * 64];    // 24 KB
  __shared__ __align__(16) int8_t lB[6][128 * 64];   // 48 KB
  __shared__ float red4[4];

  // bijective XCD swizzle (m204)
  const int nwg = gridDim.x;
  const int q = nwg >> 3, rr = nwg & 7;
  const int xcd = blockIdx.x & 7, sub = blockIdx.x >> 3;
  const int wg = (xcd < rr ? xcd * (q + 1) : rr * (q + 1) + (xcd - rr) * q) + sub;
  const int bx = wg % GN;   // n-tile fastest: 12 blocks share an A strip
  const int by = wg / GN;
  const int tid0 = by * GN + bx;

  const int t = threadIdx.x;
  const int lane = t & 63;
  const int wave = t >> 6;      // 0..3
  const int wr = wave >> 1;     // 0..1 (M)
  const int wc = wave & 1;      // 0..1 (N)
  const int r15 = lane & 15;
  const int q4 = lane >> 4;
  const size_t m0 = (size_t)by * 64;
  const int n0 = bx * 128;

  const int8_t* Ab = A + m0 * (size_t)K;
  const int8_t* Bb = B + (size_t)n0 * (size_t)K;

  // Staging: linear LDS fill; XOR slot-swizzle f(row)=(row>>1)&3 pre-applied
  // on the GLOBAL source (both-sides rule; 0 conflicts measured r4-r13).
  // Per chunk: A = 1 load/thread (64 rows), B = 2 loads/thread (128 rows).
  const int row0 = t >> 2;                      // 0..63
  const int ss = (t & 3) ^ ((row0 >> 1) & 3);
  const int ubase = __builtin_amdgcn_readfirstlane((t & 192) * 16);  // wave*1024
  const size_t srcA  = (size_t)row0 * K + (size_t)(ss * 16);
  const size_t srcB1 = (size_t)(row0 + 64) * K + (size_t)(ss * 16);  // same swz

#pragma unroll
  for (int c = 0; c < 6; ++c) {
    __builtin_amdgcn_global_load_lds(GPTR(Ab + c * 64 + srcA),  LPTR(&lA[c][ubase]), 16, 0, 0);
    __builtin_amdgcn_global_load_lds(GPTR(Bb + c * 64 + srcA),  LPTR(&lB[c][ubase]), 16, 0, 0);
    __builtin_amdgcn_global_load_lds(GPTR(Bb + c * 64 + srcB1), LPTR(&lB[c][4096 + ubase]), 16, 0, 0);
  }
  asm volatile("s_waitcnt vmcnt(0)" ::: "memory");
  __syncthreads();   // everything resident; no more barriers until epilogue

  v4i acc[2][4] = {};
#pragma unroll
  for (int kt = 0; kt < 6; ++kt) {
    v4i af[2], bf[4];
#pragma unroll
    for (int fr = 0; fr < 2; ++fr) {
      const int row = wr * 32 + fr * 16 + r15;
      const int slot = q4 ^ ((row >> 1) & 3);
      af[fr] = *(const v4i*)(&lA[kt][row * 64 + slot * 16]);
    }
#pragma unroll
    for (int fc = 0; fc < 4; ++fc) {
      const int row = wc * 64 + fc * 16 + r15;
      const int slot = q4 ^ ((row >> 1) & 3);
      bf[fc] = *(const v4i*)(&lB[kt][row * 64 + slot * 16]);
    }
#pragma unroll
    for (int fr = 0; fr < 2; ++fr)
#pragma unroll
      for (int fc = 0; fc < 4; ++fc)
        acc[fr][fc] = __builtin_amdgcn_mfma_i32_16x16x64_i8(af[fr], bf[fc], acc[fr][fc], 0, 0, 0);
  }

  const int rb = q4 * 4;

  if constexpr (EPI == 0) {
    // max over m of (acc+bias) = int-max over m, one add per column.
    float lm = -3.4e38f;
#pragma unroll
    for (int fc = 0; fc < 4; ++fc) {
      int im = acc[0][fc][0];
#pragma unroll
      for (int fr = 0; fr < 2; ++fr)
#pragma unroll
        for (int r = 0; r < 4; ++r) im = max(im, acc[fr][fc][r]);
      lm = fmaxf(lm, (float)im + bias[n0 + wc * 64 + fc * 16 + r15]);
    }
    lm = wave_max(lm);
    if (lane == 0) red4[wave] = lm;
    __syncthreads();
    if (t == 0)
      partial[tid0] = fmaxf(fmaxf(red4[0], red4[1]), fmaxf(red4[2], red4[3]));
  } else {
    const float sx = __uint_as_float(scal[0]) / 127.0f;
    const float sw = __uint_as_float(scal[1]) / 127.0f;
    const float s1 = sw * sx;
    const float sh = __uint_as_float(scal[3]) / 127.0f;
    const float inv_sh = __builtin_amdgcn_rcpf(sh);
    __syncthreads();                 // all waves done reading lA/lB
    int8_t* qt = (int8_t*)lA;        // 8 KiB repack tile (64x128), swizzled
#pragma unroll
    for (int fc = 0; fc < 4; ++fc) {
      const int col = wc * 64 + fc * 16 + r15;
      const float bvs = bias[n0 + col] * s1;
#pragma unroll
      for (int fr = 0; fr < 2; ++fr) {
        const int rowb = wr * 32 + fr * 16 + rb;
#pragma unroll
        for (int r = 0; r < 4; ++r) {
          const float f = fmaf((float)acc[fr][fc][r], s1, bvs);
          const float g = gelu_tanh(f);
          const float qv = rintf(fminf(fmaxf(g * inv_sh, -128.0f), 127.0f));
          qt[(rowb + r) * 128 + (col ^ (q4 << 4))] = (int8_t)(int)qv;
        }
      }
    }
    __syncthreads();
#pragma unroll
    for (int v = 0; v < 2; ++v) {
      const int idx = v * 256 + t;
      const int row = idx >> 3;            // 0..63
      const int colb = (idx & 7) * 16;
      const int swz = ((row >> 2) & 3) << 4;
      *(v4i*)(qh + (m0 + row) * (size_t)N + n0 + colb) =
          *(const v4i*)(qt + row * 128 + (colb ^ swz));
    }
  }
}

// ---------------------------------------------------------------------------
// fc2 (r13-verified, ~12 us): 512 threads = 8 waves, tile 128x128, BK=64,
// 2-buffer 1-barrier loop. KT=24 amortizes the per-kt drain.
// ---------------------------------------------------------------------------
__global__ __launch_bounds__(512, 4)
void gemm2_out_kernel(const int8_t* __restrict__ A, const int8_t* __restrict__ B,
                      const float* __restrict__ bias, const unsigned* __restrict__ scal,
                      float* __restrict__ out_f32, int N, int K, int GN) {
  __shared__ __align__(16) int8_t lA[2][128 * 64];
  __shared__ __align__(16) int8_t lB[2][128 * 64];

  const int nwg = gridDim.x;
  const int q = nwg >> 3, rr = nwg & 7;
  const int xcd = blockIdx.x & 7, sub = blockIdx.x >> 3;
  const int wg = (xcd < rr ? xcd * (q + 1) : rr * (q + 1) + (xcd - rr) * q) + sub;
  const int bx = wg % GN;
  const int by = wg / GN;

  const int t = threadIdx.x;
  const int lane = t & 63;
  const int wave = t >> 6;
  const int wr = wave >> 1;
  const int wc = wave & 1;
  const size_t m0 = (size_t)by * 128;
  const int n0 = bx * 128;

  const int8_t* Ab = A + m0 * (size_t)K;
  const int8_t* Bb = B + (size_t)n0 * (size_t)K;

  v4i acc[2][4] = {};
  const int KT = K >> 6;  // 24

  const int row0 = t >> 2;
  const int ss = (t & 3) ^ ((row0 >> 1) & 3);
  const int ubase = __builtin_amdgcn_readfirstlane(wave * 1024);
  const size_t srcA0 = (size_t)row0 * K + (size_t)(ss * 16);

  auto stage = [&](int buf, int kt) {
    const int8_t* ga = Ab + kt * 64;
    const int8_t* gb = Bb + kt * 64;
    __builtin_amdgcn_global_load_lds(GPTR(ga + srcA0), LPTR(&lA[buf][ubase]), 16, 0, 0);
    __builtin_amdgcn_global_load_lds(GPTR(gb + srcA0), LPTR(&lB[buf][ubase]), 16, 0, 0);
  };

  const int r15 = lane & 15;
  const int q4 = lane >> 4;

  auto compute = [&](int buf) {
    v4i af[2], bf[4];
#pragma unroll
    for (int fr = 0; fr < 2; ++fr) {
      const int row = wr * 32 + fr * 16 + r15;
      const int slot = q4 ^ ((row >> 1) & 3);
      af[fr] = *(const v4i*)(&lA[buf][row * 64 + slot * 16]);
    }
#pragma unroll
    for (int fc = 0; fc < 4; ++fc) {
      const int row = wc * 64 + fc * 16 + r15;
      const int slot = q4 ^ ((row >> 1) & 3);
      bf[fc] = *(const v4i*)(&lB[buf][row * 64 + slot * 16]);
    }
#pragma unroll
    for (int fr = 0; fr < 2; ++fr)
#pragma unroll
      for (int fc = 0; fc < 4; ++fc)
        acc[fr][fc] = __builtin_amdgcn_mfma_i32_16x16x64_i8(af[fr], bf[fc], acc[fr][fc], 0, 0, 0);
  };

  stage(0, 0);
  __syncthreads();
  int cur = 0;
  for (int kt = 1; kt < KT; ++kt) {
    stage(cur ^ 1, kt);
    compute(cur);
    __syncthreads();
    cur ^= 1;
  }
  compute(cur);

  const int rb = q4 * 4;
  const float sw2 = __uint_as_float(scal[2]) / 127.0f;
  const float sh = __uint_as_float(scal[3]) / 127.0f;
  const float s2 = sw2 * ((127.0f * sh) / 127.0f);
#pragma unroll
  for (int fc = 0; fc < 4; ++fc) {
    const int n = n0 + wc * 64 + fc * 16 + r15;
    const float bvs = bias[n] * s2;
#pragma unroll
    for (int fr = 0; fr < 2; ++fr)
#pragma unroll
      for (int r = 0; r < 4; ++r) {
        const size_t m = m0 + (size_t)(wr * 32 + fr * 16 + rb + r);
        out_f32[m * (size_t)N + n] = fmaf((float)acc[fr][fc][r], s2, bvs);
      }
  }
}

extern "C" void kernel_launch(void* const* d_in, const int* in_sizes, int n_in,
                              void* d_out, int out_size, void* d_ws, size_t ws_size,
                              hipStream_t stream) {
  const float* x   = (const float*)d_in[0];
  const float* sxp = (const float*)d_in[1];
  const float* w1  = (const float*)d_in[2];
  const float* b1  = (const float*)d_in[3];
  const float* w2  = (const float*)d_in[4];
  const float* b2  = (const float*)d_in[5];

  const int H = in_sizes[3];      // 1536
  const int D = in_sizes[5];      // 384
  const int M = in_sizes[0] / D;  // 25216
  const int GM1 = M / 64;         // 394 (fc1 m-tiles)
  const int GM2 = M / 128;        // 197 (fc2 m-tiles)
  const int GN1 = H / 128;        // 12
  const int GN2 = D / 128;        // 3

  uint8_t* ws = (uint8_t*)d_ws;
  unsigned* scal = (unsigned*)ws;  // [0]=max|x2| [1]=max|w1| [2]=max|w2| [3]=max|g|
  size_t off = 256;
  float* partial = (float*)(ws + off); off += 32768;  // 4728 fc1 blocks
  int8_t* qx  = (int8_t*)(ws + off); off += (size_t)M * D;
  int8_t* qw1 = (int8_t*)(ws + off); off += (size_t)H * D;
  int8_t* qw2 = (int8_t*)(ws + off); off += (size_t)D * H;
  int8_t* qh  = (int8_t*)(ws + off); off += (size_t)M * H;
  (void)ws_size; (void)n_in; (void)out_size;

  hipMemsetAsync(scal, 0, 16, stream);

  absmax3_kernel<<<dim3(768), dim3(256), 0, stream>>>(
      x, M * D / 4, sxp, w1, H * D / 4, w2, D * H / 4, scal);

  quantize3_kernel<<<dim3(2304), dim3(256), 0, stream>>>(
      x, M * D / 4, sxp, w1, H * D / 4, w2, D * H / 4, scal, qx, qw1, qw2);

  dim3 g1(GN1 * GM1);  // 4728
  fc1_kernel<0><<<g1, dim3(256), 0, stream>>>(qx, qw1, b1, scal, partial, nullptr, H, D, GN1);
  reduce_scale_kernel<<<1, 256, 0, stream>>>(partial, GM1 * GN1, scal);
  fc1_kernel<1><<<g1, dim3(256), 0, stream>>>(qx, qw1, b1, scal, nullptr, qh, H, D, GN1);

  dim3 g2(GN2 * GM2);  // 591
  gemm2_out_kernel<<<g2, dim3(512), 0, stream>>>(qh, qw2, b2, scal, (float*)d_out, D, H, GN2);
}